// Round 1
// baseline (1124.907 us; speedup 1.0000x reference)
//
#include <hip/hip_runtime.h>

// ---------------------------------------------------------------------------
// SlotAttention forward, MI355X. B=64,S=16,F=4096,D=512,H=2048,3 iters.
// Strategy: fold W_k/W_v into slot-side (q' = q@Wk, updates = (attn@f)@Wv^T),
// stream f_norm (bf16, 256MB) twice per iteration. Memory-bound design.
// ---------------------------------------------------------------------------

typedef __bf16 bf16x8 __attribute__((ext_vector_type(8)));
typedef float  f32x4  __attribute__((ext_vector_type(4)));

#define DEV static __device__ __forceinline__

DEV float bf2f_lo(unsigned int u) { union { unsigned int i; float f; } v; v.i = u << 16; return v.f; }
DEV float bf2f_hi(unsigned int u) { union { unsigned int i; float f; } v; v.i = u & 0xFFFF0000u; return v.f; }
DEV unsigned short f2bf(float f) {
  union { float f; unsigned int i; } v; v.f = f;
  return (unsigned short)((v.i + 0x7FFFu + ((v.i >> 16) & 1u)) >> 16);
}

// ---------------------------------------------------------------------------
// LayerNorm over rows of length 512 (one wave per row). fp32 in, bf16 out
// (+ optional fp32 out). var is population variance (ddof=0), eps=1e-5.
// ---------------------------------------------------------------------------
template<int OUTF>
__global__ __launch_bounds__(256) void ln512_kernel(
    const float* __restrict__ X, const float* __restrict__ g,
    const float* __restrict__ b, unsigned short* __restrict__ Yb,
    float* __restrict__ Yf, int R) {
  int wave = (blockIdx.x << 2) | (threadIdx.x >> 6);
  int lane = threadIdx.x & 63;
  if (wave >= R) return;
  const float4* xp = reinterpret_cast<const float4*>(X + (size_t)wave * 512);
  float4 x0 = xp[lane * 2], x1 = xp[lane * 2 + 1];
  float xv[8] = {x0.x, x0.y, x0.z, x0.w, x1.x, x1.y, x1.z, x1.w};
  float s = 0.f, q = 0.f;
#pragma unroll
  for (int j = 0; j < 8; ++j) { s += xv[j]; q += xv[j] * xv[j]; }
#pragma unroll
  for (int off = 32; off; off >>= 1) { s += __shfl_xor(s, off); q += __shfl_xor(q, off); }
  float mu = s * (1.0f / 512.0f);
  float var = q * (1.0f / 512.0f) - mu * mu;
  float rstd = rsqrtf(var + 1e-5f);
  const float4* gp = reinterpret_cast<const float4*>(g);
  const float4* bp = reinterpret_cast<const float4*>(b);
  float4 g0 = gp[lane * 2], g1 = gp[lane * 2 + 1];
  float4 b0 = bp[lane * 2], b1 = bp[lane * 2 + 1];
  float gv[8] = {g0.x, g0.y, g0.z, g0.w, g1.x, g1.y, g1.z, g1.w};
  float bv[8] = {b0.x, b0.y, b0.z, b0.w, b1.x, b1.y, b1.z, b1.w};
  float y[8];
  unsigned short u[8];
#pragma unroll
  for (int j = 0; j < 8; ++j) { y[j] = (xv[j] - mu) * rstd * gv[j] + bv[j]; u[j] = f2bf(y[j]); }
  uint4 o = make_uint4(
      (unsigned)u[0] | ((unsigned)u[1] << 16), (unsigned)u[2] | ((unsigned)u[3] << 16),
      (unsigned)u[4] | ((unsigned)u[5] << 16), (unsigned)u[6] | ((unsigned)u[7] << 16));
  reinterpret_cast<uint4*>(Yb + (size_t)wave * 512)[lane] = o;
  if (OUTF) {
    float4* yf = reinterpret_cast<float4*>(Yf + (size_t)wave * 512);
    yf[lane * 2]     = make_float4(y[0], y[1], y[2], y[3]);
    yf[lane * 2 + 1] = make_float4(y[4], y[5], y[6], y[7]);
  }
}

// ---------------------------------------------------------------------------
// fp32 -> bf16 flat convert (weights, n multiple of 4)
// ---------------------------------------------------------------------------
__global__ void cvt_bf16_kernel(const float* __restrict__ in, unsigned short* __restrict__ out, int n4) {
  int i = blockIdx.x * 256 + threadIdx.x;
  if (i >= n4) return;
  float4 v = reinterpret_cast<const float4*>(in)[i];
  unsigned int lo = (unsigned)f2bf(v.x) | ((unsigned)f2bf(v.y) << 16);
  unsigned int hi = (unsigned)f2bf(v.z) | ((unsigned)f2bf(v.w) << 16);
  reinterpret_cast<uint2*>(out)[i] = make_uint2(lo, hi);
}

// Transpose+convert Wk [512,512]: out[i][j] = in[j][i] (once, small)
__global__ void transpose_cvt_kernel(const float* __restrict__ in, unsigned short* __restrict__ out) {
  int t = blockIdx.x * 256 + threadIdx.x;
  int i = t >> 9, j = t & 511;
  out[t] = f2bf(in[j * 512 + i]);
}

// ---------------------------------------------------------------------------
// Generic NT bf16 MFMA GEMM: C[M,N] = act(A[M,K] @ B[N,K]^T + bias) (+res)
// block 256 (4 waves, 2x2), tile 64x64, wave tile 32x32. M%64==N%64==K%32==0.
// ---------------------------------------------------------------------------
template<int RELU, int BIAS, int RES, int OUTF, int OUTB>
__global__ __launch_bounds__(256) void gemm_nt(
    const unsigned short* __restrict__ A, const unsigned short* __restrict__ Bm,
    const float* __restrict__ bias, const float* res,
    float* Cf, unsigned short* __restrict__ Cb, int M, int N, int K) {
  int lane = threadIdx.x & 63;
  int w = threadIdx.x >> 6;
  int wr = w >> 1, wc = w & 1;
  int m0 = blockIdx.y * 64 + wr * 32;
  int n0 = blockIdx.x * 64 + wc * 32;
  int lo = lane & 15, hi = lane >> 4;
  const unsigned short* Ap = A + (size_t)(m0 + lo) * K + (hi << 3);
  const unsigned short* Bp = Bm + (size_t)(n0 + lo) * K + (hi << 3);
  f32x4 acc[2][2];
#pragma unroll
  for (int i = 0; i < 2; ++i)
#pragma unroll
    for (int j = 0; j < 2; ++j) acc[i][j] = f32x4{0.f, 0.f, 0.f, 0.f};
  for (int kk = 0; kk < K; kk += 32) {
    bf16x8 a0 = *reinterpret_cast<const bf16x8*>(Ap + kk);
    bf16x8 a1 = *reinterpret_cast<const bf16x8*>(Ap + (size_t)16 * K + kk);
    bf16x8 bb0 = *reinterpret_cast<const bf16x8*>(Bp + kk);
    bf16x8 bb1 = *reinterpret_cast<const bf16x8*>(Bp + (size_t)16 * K + kk);
    acc[0][0] = __builtin_amdgcn_mfma_f32_16x16x32_bf16(a0, bb0, acc[0][0], 0, 0, 0);
    acc[0][1] = __builtin_amdgcn_mfma_f32_16x16x32_bf16(a0, bb1, acc[0][1], 0, 0, 0);
    acc[1][0] = __builtin_amdgcn_mfma_f32_16x16x32_bf16(a1, bb0, acc[1][0], 0, 0, 0);
    acc[1][1] = __builtin_amdgcn_mfma_f32_16x16x32_bf16(a1, bb1, acc[1][1], 0, 0, 0);
  }
#pragma unroll
  for (int i = 0; i < 2; ++i)
#pragma unroll
    for (int j = 0; j < 2; ++j) {
      int n = n0 + j * 16 + lo;
      float bvv = BIAS ? bias[n] : 0.f;
#pragma unroll
      for (int r = 0; r < 4; ++r) {
        int m = m0 + i * 16 + (hi << 2) + r;
        float v = acc[i][j][r] + bvv;
        if (RELU) v = fmaxf(v, 0.f);
        if (RES) v += res[(size_t)m * N + n];
        if (OUTF) Cf[(size_t)m * N + n] = v;
        if (OUTB) Cb[(size_t)m * N + n] = f2bf(v);
      }
    }
}

// ---------------------------------------------------------------------------
// dots = q' @ f_norm^T * scale; softmax over S=16 (in-register, shfl);
// writes attnT[b,f,s] (bf16, +EPS), per-tile f-sums, optional pre_norm fp32.
// grid (F/64, B), 4 waves, each wave one 16(s) x 16(f) MFMA tile, K=512.
// ---------------------------------------------------------------------------
__global__ __launch_bounds__(256) void dots_softmax_kernel(
    const unsigned short* __restrict__ Qp,   // [B,16,512] bf16
    const unsigned short* __restrict__ Fn,   // [B,4096,512] bf16
    unsigned short* __restrict__ attnT,      // [B,4096,16] bf16
    float* __restrict__ fsumP,               // [B,256,16]
    float* __restrict__ attn_out) {          // [B,16,4096] fp32 or null
  int b = blockIdx.y;
  int w = threadIdx.x >> 6, lane = threadIdx.x & 63;
  int lo = lane & 15, hi = lane >> 4;
  int f0 = (blockIdx.x << 6) + (w << 4);
  const unsigned short* qa = Qp + ((size_t)b * 16 + lo) * 512 + (hi << 3);
  const unsigned short* fb = Fn + ((size_t)b * 4096 + f0 + lo) * 512 + (hi << 3);
  f32x4 acc = {0.f, 0.f, 0.f, 0.f};
#pragma unroll
  for (int ks = 0; ks < 16; ++ks) {
    bf16x8 a = *reinterpret_cast<const bf16x8*>(qa + ks * 32);
    bf16x8 bb = *reinterpret_cast<const bf16x8*>(fb + ks * 32);
    acc = __builtin_amdgcn_mfma_f32_16x16x32_bf16(a, bb, acc, 0, 0, 0);
  }
  const float scale = 0.04419417382415922f;  // 512^-0.5
  float d[4], mx = -3.4e38f;
#pragma unroll
  for (int r = 0; r < 4; ++r) { d[r] = acc[r] * scale; mx = fmaxf(mx, d[r]); }
  mx = fmaxf(mx, __shfl_xor(mx, 16));
  mx = fmaxf(mx, __shfl_xor(mx, 32));
  float e[4], ss = 0.f;
#pragma unroll
  for (int r = 0; r < 4; ++r) { e[r] = __expf(d[r] - mx); ss += e[r]; }
  ss += __shfl_xor(ss, 16);
  ss += __shfl_xor(ss, 32);
  float inv = 1.f / ss;
  float cs[4];
  unsigned short u[4];
#pragma unroll
  for (int r = 0; r < 4; ++r) {
    float p = e[r] * inv;                    // pre_norm_attn (no EPS)
    if (attn_out)
      attn_out[((size_t)b * 16 + (hi << 2) + r) * 4096 + f0 + lo] = p;
    unsigned short uu = f2bf(p + 1e-8f);
    u[r] = uu;
    cs[r] = bf2f_lo(uu);                     // rounded value -> consistent fsum
  }
  unsigned int w0 = (unsigned)u[0] | ((unsigned)u[1] << 16);
  unsigned int w1 = (unsigned)u[2] | ((unsigned)u[3] << 16);
  *reinterpret_cast<uint2*>(attnT + ((size_t)b * 4096 + f0 + lo) * 16 + (hi << 2)) = make_uint2(w0, w1);
#pragma unroll
  for (int m = 1; m < 16; m <<= 1) {
#pragma unroll
    for (int r = 0; r < 4; ++r) cs[r] += __shfl_xor(cs[r], m);
  }
  if (lo == 0) {
    int tile = f0 >> 4;
    float* dst = fsumP + ((size_t)b * 256 + tile) * 16 + (hi << 2);
    dst[0] = cs[0]; dst[1] = cs[1]; dst[2] = cs[2]; dst[3] = cs[3];
  }
}

// fsum reduce: inv_fsum[b,s] = 1 / sum_tiles fsumP
__global__ void fsum_reduce_kernel(const float* __restrict__ fsumP, float* __restrict__ invf) {
  int t = blockIdx.x * 256 + threadIdx.x;
  if (t >= 1024) return;
  int b = t >> 4, s = t & 15;
  const float* p = fsumP + (size_t)b * 256 * 16 + s;
  float acc = 0.f;
#pragma unroll 8
  for (int i = 0; i < 256; ++i) acc += p[i * 16];
  invf[t] = 1.f / acc;
}

// ---------------------------------------------------------------------------
// updates' partials: updP[b,ch,s,d] = sum_{f in chunk} attn[b,s,f]*f_norm[b,f,d]
// 1 wave/block, lane owns 8 d-columns (16B coalesced), acc[16][8] in VGPRs.
// ---------------------------------------------------------------------------
__global__ __launch_bounds__(64) void updates_partial_kernel(
    const unsigned short* __restrict__ attnT, const unsigned short* __restrict__ Fn,
    float* __restrict__ updP) {
  int b = blockIdx.y, ch = blockIdx.x;  // 32 chunks x 128 f
  int lane = threadIdx.x;
  const unsigned short* fb = Fn + ((size_t)b * 4096 + ch * 128) * 512 + lane * 8;
  const unsigned short* ab = attnT + ((size_t)b * 4096 + ch * 128) * 16;
  float acc[16][8];
#pragma unroll
  for (int s = 0; s < 16; ++s)
#pragma unroll
    for (int j = 0; j < 8; ++j) acc[s][j] = 0.f;
  for (int f = 0; f < 128; ++f) {
    uint4 a0 = *reinterpret_cast<const uint4*>(ab + (size_t)f * 16);
    uint4 a1 = *reinterpret_cast<const uint4*>(ab + (size_t)f * 16 + 8);
    uint4 xr = *reinterpret_cast<const uint4*>(fb + (size_t)f * 512);
    float x[8];
    x[0] = bf2f_lo(xr.x); x[1] = bf2f_hi(xr.x); x[2] = bf2f_lo(xr.y); x[3] = bf2f_hi(xr.y);
    x[4] = bf2f_lo(xr.z); x[5] = bf2f_hi(xr.z); x[6] = bf2f_lo(xr.w); x[7] = bf2f_hi(xr.w);
    float at[16];
    at[0] = bf2f_lo(a0.x); at[1] = bf2f_hi(a0.x); at[2] = bf2f_lo(a0.y); at[3] = bf2f_hi(a0.y);
    at[4] = bf2f_lo(a0.z); at[5] = bf2f_hi(a0.z); at[6] = bf2f_lo(a0.w); at[7] = bf2f_hi(a0.w);
    at[8] = bf2f_lo(a1.x); at[9] = bf2f_hi(a1.x); at[10] = bf2f_lo(a1.y); at[11] = bf2f_hi(a1.y);
    at[12] = bf2f_lo(a1.z); at[13] = bf2f_hi(a1.z); at[14] = bf2f_lo(a1.w); at[15] = bf2f_hi(a1.w);
#pragma unroll
    for (int s = 0; s < 16; ++s)
#pragma unroll
      for (int j = 0; j < 8; ++j) acc[s][j] = fmaf(at[s], x[j], acc[s][j]);
  }
  float* out = updP + ((size_t)(b * 32 + ch) * 16) * 512 + lane * 8;
#pragma unroll
  for (int s = 0; s < 16; ++s) {
    *reinterpret_cast<float4*>(out + (size_t)s * 512)     = make_float4(acc[s][0], acc[s][1], acc[s][2], acc[s][3]);
    *reinterpret_cast<float4*>(out + (size_t)s * 512 + 4) = make_float4(acc[s][4], acc[s][5], acc[s][6], acc[s][7]);
  }
}

// reduce partials over 32 chunks, apply inv_fsum, emit bf16 updates' [B*S,512]
__global__ void updates_reduce_kernel(const float* __restrict__ updP,
                                      const float* __restrict__ invf,
                                      unsigned short* __restrict__ outb) {
  int t = blockIdx.x * 256 + threadIdx.x;  // 524288
  int s = (t >> 9) & 15, b = t >> 13;
  float acc = 0.f;
  const float* p = updP + ((size_t)(b * 32) * 16 + s) * 512 + (t & 511);
#pragma unroll 8
  for (int ch = 0; ch < 32; ++ch) acc += p[(size_t)ch * 16 * 512];
  outb[t] = f2bf(acc * invf[(b << 4) | s]);
}

// ---------------------------------------------------------------------------
// GRU combine (torch GRUCell semantics) + fused LayerNorm(mlp_ln) -> h_ln bf16
// block = one row (512 cols, 256 threads x 2)
// ---------------------------------------------------------------------------
__global__ __launch_bounds__(256) void gru_ln_kernel(
    const float* __restrict__ gi, const float* __restrict__ gh,
    const float* __restrict__ sn, const float* __restrict__ mg,
    const float* __restrict__ mb, float* __restrict__ slots,
    unsigned short* __restrict__ hln) {
  __shared__ float red[8];
  int row = blockIdx.x;
  int t = threadIdx.x;
  const float* gir = gi + (size_t)row * 1536;
  const float* ghr = gh + (size_t)row * 1536;
  float2 ir = *reinterpret_cast<const float2*>(gir + t * 2);
  float2 iz = *reinterpret_cast<const float2*>(gir + 512 + t * 2);
  float2 in_ = *reinterpret_cast<const float2*>(gir + 1024 + t * 2);
  float2 hr = *reinterpret_cast<const float2*>(ghr + t * 2);
  float2 hz = *reinterpret_cast<const float2*>(ghr + 512 + t * 2);
  float2 hn = *reinterpret_cast<const float2*>(ghr + 1024 + t * 2);
  float2 hp = *reinterpret_cast<const float2*>(sn + (size_t)row * 512 + t * 2);
  float h[2], iv[2] = {in_.x, in_.y}, hv[2] = {hn.x, hn.y};
  float rr[2] = {ir.x + hr.x, ir.y + hr.y}, zz[2] = {iz.x + hz.x, iz.y + hz.y};
  float pp[2] = {hp.x, hp.y};
#pragma unroll
  for (int k = 0; k < 2; ++k) {
    float r = 1.f / (1.f + __expf(-rr[k]));
    float z = 1.f / (1.f + __expf(-zz[k]));
    float a = iv[k] + r * hv[k];
    float ee = __expf(-2.f * fabsf(a));
    float nt = (1.f - ee) / (1.f + ee);
    float n = copysignf(nt, a);
    h[k] = (1.f - z) * n + z * pp[k];
  }
  *reinterpret_cast<float2*>(slots + (size_t)row * 512 + t * 2) = make_float2(h[0], h[1]);
  float s = h[0] + h[1], q = h[0] * h[0] + h[1] * h[1];
#pragma unroll
  for (int off = 32; off; off >>= 1) { s += __shfl_xor(s, off); q += __shfl_xor(q, off); }
  int w = t >> 6, lane = t & 63;
  if (lane == 0) { red[w] = s; red[4 + w] = q; }
  __syncthreads();
  s = red[0] + red[1] + red[2] + red[3];
  q = red[4] + red[5] + red[6] + red[7];
  float mu = s * (1.f / 512.f);
  float var = q * (1.f / 512.f) - mu * mu;
  float rstd = rsqrtf(var + 1e-5f);
  float y0 = (h[0] - mu) * rstd * mg[t * 2] + mb[t * 2];
  float y1 = (h[1] - mu) * rstd * mg[t * 2 + 1] + mb[t * 2 + 1];
  *reinterpret_cast<unsigned int*>(hln + (size_t)row * 512 + t * 2) =
      (unsigned)f2bf(y0) | ((unsigned)f2bf(y1) << 16);
}

// ---------------------------------------------------------------------------
extern "C" void kernel_launch(void* const* d_in, const int* in_sizes, int n_in,
                              void* d_out, int out_size, void* d_ws, size_t ws_size,
                              hipStream_t stream) {
  const float* slots_in  = (const float*)d_in[0];
  const float* features  = (const float*)d_in[1];
  const float* ln_feat_g = (const float*)d_in[2];
  const float* ln_feat_b = (const float*)d_in[3];
  const float* ln_slot_g = (const float*)d_in[4];
  const float* ln_slot_b = (const float*)d_in[5];
  const float* w_k  = (const float*)d_in[6];
  const float* w_v  = (const float*)d_in[7];
  const float* w_q  = (const float*)d_in[8];
  const float* w_ih = (const float*)d_in[9];
  const float* w_hh = (const float*)d_in[10];
  const float* b_ih = (const float*)d_in[11];
  const float* b_hh = (const float*)d_in[12];
  const float* mlp_ln_g = (const float*)d_in[13];
  const float* mlp_ln_b = (const float*)d_in[14];
  const float* w1 = (const float*)d_in[15];
  const float* b1 = (const float*)d_in[16];
  const float* w2 = (const float*)d_in[17];
  const float* b2 = (const float*)d_in[18];

  char* ws = (char*)d_ws;
  size_t off = 0;
  auto alloc = [&](size_t bytes) {
    char* p = ws + off;
    off += (bytes + 255) & ~(size_t)255;
    return p;
  };
  unsigned short* f_norm  = (unsigned short*)alloc((size_t)64 * 4096 * 512 * 2);  // 256MB
  unsigned short* attnT   = (unsigned short*)alloc((size_t)64 * 4096 * 16 * 2);   // 8MB
  unsigned short* q_bf    = (unsigned short*)alloc(1024 * 512 * 2);
  unsigned short* qp_bf   = (unsigned short*)alloc(1024 * 512 * 2);
  float*          s_n_f   = (float*)alloc(1024 * 512 * 4);
  unsigned short* s_n_bf  = (unsigned short*)alloc(1024 * 512 * 2);
  float*          fsumP   = (float*)alloc(64 * 256 * 16 * 4);
  float*          invf    = (float*)alloc(1024 * 4);
  float*          updP    = (float*)alloc((size_t)64 * 32 * 16 * 512 * 4);        // 64MB
  unsigned short* updp_bf = (unsigned short*)alloc(1024 * 512 * 2);
  unsigned short* upd_bf  = (unsigned short*)alloc(1024 * 512 * 2);
  float*          gi      = (float*)alloc(1024 * 1536 * 4);
  float*          gh      = (float*)alloc(1024 * 1536 * 4);
  float*          slots_c = (float*)alloc(1024 * 512 * 4);
  unsigned short* hln_bf  = (unsigned short*)alloc(1024 * 512 * 2);
  unsigned short* hm_bf   = (unsigned short*)alloc((size_t)1024 * 2048 * 2);
  unsigned short* Wq_bf   = (unsigned short*)alloc(512 * 512 * 2);
  unsigned short* WkT_bf  = (unsigned short*)alloc(512 * 512 * 2);
  unsigned short* Wv_bf   = (unsigned short*)alloc(512 * 512 * 2);
  unsigned short* Wih_bf  = (unsigned short*)alloc(1536 * 512 * 2);
  unsigned short* Whh_bf  = (unsigned short*)alloc(1536 * 512 * 2);
  unsigned short* W1_bf   = (unsigned short*)alloc((size_t)2048 * 512 * 2);
  unsigned short* W2_bf   = (unsigned short*)alloc((size_t)512 * 2048 * 2);

  float* out_slots = (float*)d_out;               // [64,16,512]
  float* out_attn  = out_slots + 1024 * 512;      // [64,16,4096]

  // --- weight conversions (once) ---
  cvt_bf16_kernel<<<dim3(256), dim3(256), 0, stream>>>(w_q, Wq_bf, 65536);
  cvt_bf16_kernel<<<dim3(256), dim3(256), 0, stream>>>(w_v, Wv_bf, 65536);
  cvt_bf16_kernel<<<dim3(768), dim3(256), 0, stream>>>(w_ih, Wih_bf, 196608);
  cvt_bf16_kernel<<<dim3(768), dim3(256), 0, stream>>>(w_hh, Whh_bf, 196608);
  cvt_bf16_kernel<<<dim3(1024), dim3(256), 0, stream>>>(w1, W1_bf, 262144);
  cvt_bf16_kernel<<<dim3(1024), dim3(256), 0, stream>>>(w2, W2_bf, 262144);
  transpose_cvt_kernel<<<dim3(1024), dim3(256), 0, stream>>>(w_k, WkT_bf);

  // --- f_norm = LN(features) -> bf16 ---
  ln512_kernel<0><<<dim3(65536), dim3(256), 0, stream>>>(
      features, ln_feat_g, ln_feat_b, f_norm, nullptr, 262144);

  for (int it = 0; it < 3; ++it) {
    const float* slots_src = (it == 0) ? slots_in : slots_c;
    // s_n = LN(slots)
    ln512_kernel<1><<<dim3(256), dim3(256), 0, stream>>>(
        slots_src, ln_slot_g, ln_slot_b, s_n_bf, s_n_f, 1024);
    // q = s_n @ Wq^T
    gemm_nt<0, 0, 0, 0, 1><<<dim3(8, 16), dim3(256), 0, stream>>>(
        s_n_bf, Wq_bf, nullptr, nullptr, nullptr, q_bf, 1024, 512, 512);
    // q' = q @ Wk  (= q @ WkT^T)
    gemm_nt<0, 0, 0, 0, 1><<<dim3(8, 16), dim3(256), 0, stream>>>(
        q_bf, WkT_bf, nullptr, nullptr, nullptr, qp_bf, 1024, 512, 512);
    // dots + softmax over slots + attnT + fsum partials (+ pre_norm out on last)
    dots_softmax_kernel<<<dim3(64, 64), dim3(256), 0, stream>>>(
        qp_bf, f_norm, attnT, fsumP, (it == 2) ? out_attn : nullptr);
    fsum_reduce_kernel<<<dim3(4), dim3(256), 0, stream>>>(fsumP, invf);
    // updates' = attn_norm @ f_norm
    updates_partial_kernel<<<dim3(32, 64), dim3(64), 0, stream>>>(attnT, f_norm, updP);
    updates_reduce_kernel<<<dim3(2048), dim3(256), 0, stream>>>(updP, invf, updp_bf);
    // updates = updates' @ Wv^T
    gemm_nt<0, 0, 0, 0, 1><<<dim3(8, 16), dim3(256), 0, stream>>>(
        updp_bf, Wv_bf, nullptr, nullptr, nullptr, upd_bf, 1024, 512, 512);
    // gi = updates @ Wih^T + b_ih ; gh = s_n @ Whh^T + b_hh
    gemm_nt<0, 1, 0, 1, 0><<<dim3(24, 16), dim3(256), 0, stream>>>(
        upd_bf, Wih_bf, b_ih, nullptr, gi, nullptr, 1024, 1536, 512);
    gemm_nt<0, 1, 0, 1, 0><<<dim3(24, 16), dim3(256), 0, stream>>>(
        s_n_bf, Whh_bf, b_hh, nullptr, gh, nullptr, 1024, 1536, 512);
    // GRU combine + LN(mlp_ln) -> slots_c, h_ln
    gru_ln_kernel<<<dim3(1024), dim3(256), 0, stream>>>(
        gi, gh, s_n_f, mlp_ln_g, mlp_ln_b, slots_c, hln_bf);
    // MLP
    gemm_nt<1, 1, 0, 0, 1><<<dim3(32, 16), dim3(256), 0, stream>>>(
        hln_bf, W1_bf, b1, nullptr, nullptr, hm_bf, 1024, 2048, 512);
    float* slot_dst = (it == 2) ? out_slots : slots_c;
    gemm_nt<0, 1, 1, 1, 0><<<dim3(8, 16), dim3(256), 0, stream>>>(
        hm_bf, W2_bf, b2, slots_c, slot_dst, nullptr, 1024, 512, 2048);
  }
  (void)in_sizes; (void)n_in; (void)out_size; (void)ws_size;
}

// Round 2
// 1028.108 us; speedup vs baseline: 1.0942x; 1.0942x over previous
//
#include <hip/hip_runtime.h>

// ---------------------------------------------------------------------------
// SlotAttention forward, MI355X. B=64,S=16,F=4096,D=512,H=2048,3 iters.
// R2: folded composite weights (wk^T wq, wih wv), merged qp+gh GEMM,
// MFMA updates-GEMM against one-time f_normT transpose (replaces VALU pass).
// ---------------------------------------------------------------------------

typedef __bf16 bf16x8 __attribute__((ext_vector_type(8)));
typedef float  f32x4  __attribute__((ext_vector_type(4)));

#define DEV static __device__ __forceinline__

DEV float bf2f_lo(unsigned int u) { union { unsigned int i; float f; } v; v.i = u << 16; return v.f; }
DEV unsigned short f2bf(float f) {
  union { float f; unsigned int i; } v; v.f = f;
  return (unsigned short)((v.i + 0x7FFFu + ((v.i >> 16) & 1u)) >> 16);
}

// ---------------------------------------------------------------------------
// LayerNorm rows of 512 (one wave per row). fp32 in, bf16 out (+opt fp32).
// ---------------------------------------------------------------------------
template<int OUTF>
__global__ __launch_bounds__(256) void ln512_kernel(
    const float* __restrict__ X, const float* __restrict__ g,
    const float* __restrict__ b, unsigned short* __restrict__ Yb,
    float* __restrict__ Yf, int R) {
  int wave = (blockIdx.x << 2) | (threadIdx.x >> 6);
  int lane = threadIdx.x & 63;
  if (wave >= R) return;
  const float4* xp = reinterpret_cast<const float4*>(X + (size_t)wave * 512);
  float4 x0 = xp[lane * 2], x1 = xp[lane * 2 + 1];
  float xv[8] = {x0.x, x0.y, x0.z, x0.w, x1.x, x1.y, x1.z, x1.w};
  float s = 0.f, q = 0.f;
#pragma unroll
  for (int j = 0; j < 8; ++j) { s += xv[j]; q += xv[j] * xv[j]; }
#pragma unroll
  for (int off = 32; off; off >>= 1) { s += __shfl_xor(s, off); q += __shfl_xor(q, off); }
  float mu = s * (1.0f / 512.0f);
  float var = q * (1.0f / 512.0f) - mu * mu;
  float rstd = rsqrtf(var + 1e-5f);
  const float4* gp = reinterpret_cast<const float4*>(g);
  const float4* bp = reinterpret_cast<const float4*>(b);
  float4 g0 = gp[lane * 2], g1 = gp[lane * 2 + 1];
  float4 b0 = bp[lane * 2], b1 = bp[lane * 2 + 1];
  float gv[8] = {g0.x, g0.y, g0.z, g0.w, g1.x, g1.y, g1.z, g1.w};
  float bv[8] = {b0.x, b0.y, b0.z, b0.w, b1.x, b1.y, b1.z, b1.w};
  float y[8];
  unsigned short u[8];
#pragma unroll
  for (int j = 0; j < 8; ++j) { y[j] = (xv[j] - mu) * rstd * gv[j] + bv[j]; u[j] = f2bf(y[j]); }
  uint4 o = make_uint4(
      (unsigned)u[0] | ((unsigned)u[1] << 16), (unsigned)u[2] | ((unsigned)u[3] << 16),
      (unsigned)u[4] | ((unsigned)u[5] << 16), (unsigned)u[6] | ((unsigned)u[7] << 16));
  reinterpret_cast<uint4*>(Yb + (size_t)wave * 512)[lane] = o;
  if (OUTF) {
    float4* yf = reinterpret_cast<float4*>(Yf + (size_t)wave * 512);
    yf[lane * 2]     = make_float4(y[0], y[1], y[2], y[3]);
    yf[lane * 2 + 1] = make_float4(y[4], y[5], y[6], y[7]);
  }
}

// fp32 -> bf16 flat convert
__global__ void cvt_bf16_kernel(const float* __restrict__ in, unsigned short* __restrict__ out, int n4) {
  int i = blockIdx.x * 256 + threadIdx.x;
  if (i >= n4) return;
  float4 v = reinterpret_cast<const float4*>(in)[i];
  unsigned int lo = (unsigned)f2bf(v.x) | ((unsigned)f2bf(v.y) << 16);
  unsigned int hi = (unsigned)f2bf(v.z) | ((unsigned)f2bf(v.w) << 16);
  reinterpret_cast<uint2*>(out)[i] = make_uint2(lo, hi);
}

// Transpose+convert [512,512]: out[i][j] = in[j][i]
__global__ void transpose_cvt_kernel(const float* __restrict__ in, unsigned short* __restrict__ out) {
  int t = blockIdx.x * 256 + threadIdx.x;
  int i = t >> 9, j = t & 511;
  out[t] = f2bf(in[j * 512 + i]);
}

// ---------------------------------------------------------------------------
// bf16 tile transpose: f_norm [64][4096][512] -> f_normT [64][512][4096]
// 64x64 tiles via LDS u32-pair layout [64][33] (2-way max bank aliasing).
// ---------------------------------------------------------------------------
__global__ __launch_bounds__(256) void transpose_fnorm_kernel(
    const unsigned short* __restrict__ in, unsigned short* __restrict__ out) {
  __shared__ unsigned int t[64][33];
  int b = blockIdx.z, d0 = blockIdx.y << 6, f0 = blockIdx.x << 6;
  int tid = threadIdx.x;
  {
    int f = tid >> 2, c = (tid & 3) << 4;  // 16 d-elems per thread
    const unsigned short* src = in + ((size_t)b * 4096 + f0 + f) * 512 + d0 + c;
    uint4 v0 = *reinterpret_cast<const uint4*>(src);
    uint4 v1 = *reinterpret_cast<const uint4*>(src + 8);
    unsigned int* row = &t[f][c >> 1];
    row[0] = v0.x; row[1] = v0.y; row[2] = v0.z; row[3] = v0.w;
    row[4] = v1.x; row[5] = v1.y; row[6] = v1.z; row[7] = v1.w;
  }
  __syncthreads();
  {
    int dp = tid >> 3, ff = (tid & 7) << 3;  // d-pair, 8 f-elems
    unsigned int v[8];
#pragma unroll
    for (int j = 0; j < 8; ++j) v[j] = t[ff + j][dp];
    uint4 wl, wh;
    wl.x = (v[0] & 0xFFFFu) | (v[1] << 16); wh.x = (v[0] >> 16) | (v[1] & 0xFFFF0000u);
    wl.y = (v[2] & 0xFFFFu) | (v[3] << 16); wh.y = (v[2] >> 16) | (v[3] & 0xFFFF0000u);
    wl.z = (v[4] & 0xFFFFu) | (v[5] << 16); wh.z = (v[4] >> 16) | (v[5] & 0xFFFF0000u);
    wl.w = (v[6] & 0xFFFFu) | (v[7] << 16); wh.w = (v[6] >> 16) | (v[7] & 0xFFFF0000u);
    unsigned short* dst = out + ((size_t)b * 512 + d0 + 2 * dp) * 4096 + f0 + ff;
    *reinterpret_cast<uint4*>(dst)        = wl;
    *reinterpret_cast<uint4*>(dst + 4096) = wh;
  }
}

// ---------------------------------------------------------------------------
// Generic NT bf16 MFMA GEMM: C = A[M,K] @ B[N,K]^T, block tile 32m x 128n,
// 4 waves (n-adjacent), wave tile 32x32. MODE epilogues:
// 0: bf16 plain   1: split qp(bf16,n<512)/gh(f32+bhh)   2: f32+bias
// 3: relu(v+bias)->bf16   4: v+bias+res->f32
// ---------------------------------------------------------------------------
template<int MODE>
__global__ __launch_bounds__(256) void gemm_nt(
    const unsigned short* __restrict__ A, const unsigned short* __restrict__ Bm,
    const float* __restrict__ bias, const float* __restrict__ res,
    float* __restrict__ Cf, unsigned short* __restrict__ Cb,
    int M, int N, int K) {
  int lane = threadIdx.x & 63;
  int w = threadIdx.x >> 6;
  int m0 = blockIdx.y << 5;
  int n0 = (blockIdx.x << 7) + (w << 5);
  int lo = lane & 15, hi = lane >> 4;
  const unsigned short* Ap = A + (size_t)(m0 + lo) * K + (hi << 3);
  const unsigned short* Bp = Bm + (size_t)(n0 + lo) * K + (hi << 3);
  f32x4 acc[2][2];
#pragma unroll
  for (int i = 0; i < 2; ++i)
#pragma unroll
    for (int j = 0; j < 2; ++j) acc[i][j] = f32x4{0.f, 0.f, 0.f, 0.f};
#pragma unroll 2
  for (int kk = 0; kk < K; kk += 32) {
    bf16x8 a0 = *reinterpret_cast<const bf16x8*>(Ap + kk);
    bf16x8 a1 = *reinterpret_cast<const bf16x8*>(Ap + (size_t)16 * K + kk);
    bf16x8 b0 = *reinterpret_cast<const bf16x8*>(Bp + kk);
    bf16x8 b1 = *reinterpret_cast<const bf16x8*>(Bp + (size_t)16 * K + kk);
    acc[0][0] = __builtin_amdgcn_mfma_f32_16x16x32_bf16(a0, b0, acc[0][0], 0, 0, 0);
    acc[0][1] = __builtin_amdgcn_mfma_f32_16x16x32_bf16(a0, b1, acc[0][1], 0, 0, 0);
    acc[1][0] = __builtin_amdgcn_mfma_f32_16x16x32_bf16(a1, b0, acc[1][0], 0, 0, 0);
    acc[1][1] = __builtin_amdgcn_mfma_f32_16x16x32_bf16(a1, b1, acc[1][1], 0, 0, 0);
  }
#pragma unroll
  for (int i = 0; i < 2; ++i)
#pragma unroll
    for (int j = 0; j < 2; ++j) {
      int col = n0 + (j << 4) + lo;
#pragma unroll
      for (int r = 0; r < 4; ++r) {
        int row = m0 + (i << 4) + (hi << 2) + r;
        float v = acc[i][j][r];
        if (MODE == 0) {
          Cb[(size_t)row * N + col] = f2bf(v);
        } else if (MODE == 1) {
          if (col < 512) Cb[(size_t)row * 512 + col] = f2bf(v);
          else Cf[(size_t)row * 1536 + (col - 512)] = v + bias[col - 512];
        } else if (MODE == 2) {
          Cf[(size_t)row * N + col] = v + bias[col];
        } else if (MODE == 3) {
          Cb[(size_t)row * N + col] = f2bf(fmaxf(v + bias[col], 0.f));
        } else {  // 4
          Cf[(size_t)row * N + col] = v + bias[col] + res[(size_t)row * N + col];
        }
      }
    }
}

// ---------------------------------------------------------------------------
// dots = q' @ f_norm^T * scale; softmax over S=16 (shfl); writes
// attn [b][s][f] bf16 (+EPS), per-tile f-sum partials, opt pre_norm fp32.
// grid (F/64, B), 4 waves, wave = one 16(s) x 16(f) tile, K=512.
// ---------------------------------------------------------------------------
__global__ __launch_bounds__(256) void dots_softmax_kernel(
    const unsigned short* __restrict__ Qp,   // [B,16,512] bf16
    const unsigned short* __restrict__ Fn,   // [B,4096,512] bf16
    unsigned short* __restrict__ attn_sf,    // [B,16,4096] bf16
    float* __restrict__ fsumP,               // [B,256,16]
    float* __restrict__ attn_out) {          // [B,16,4096] fp32 or null
  int b = blockIdx.y;
  int w = threadIdx.x >> 6, lane = threadIdx.x & 63;
  int lo = lane & 15, hi = lane >> 4;
  int f0 = (blockIdx.x << 6) + (w << 4);
  const unsigned short* qa = Qp + ((size_t)b * 16 + lo) * 512 + (hi << 3);
  const unsigned short* fb = Fn + ((size_t)b * 4096 + f0 + lo) * 512 + (hi << 3);
  f32x4 acc = {0.f, 0.f, 0.f, 0.f};
#pragma unroll
  for (int ks = 0; ks < 16; ++ks) {
    bf16x8 a = *reinterpret_cast<const bf16x8*>(qa + ks * 32);
    bf16x8 bb = *reinterpret_cast<const bf16x8*>(fb + ks * 32);
    acc = __builtin_amdgcn_mfma_f32_16x16x32_bf16(a, bb, acc, 0, 0, 0);
  }
  const float scale = 0.04419417382415922f;  // 512^-0.5
  float d[4], mx = -3.4e38f;
#pragma unroll
  for (int r = 0; r < 4; ++r) { d[r] = acc[r] * scale; mx = fmaxf(mx, d[r]); }
  mx = fmaxf(mx, __shfl_xor(mx, 16));
  mx = fmaxf(mx, __shfl_xor(mx, 32));
  float e[4], ss = 0.f;
#pragma unroll
  for (int r = 0; r < 4; ++r) { e[r] = __expf(d[r] - mx); ss += e[r]; }
  ss += __shfl_xor(ss, 16);
  ss += __shfl_xor(ss, 32);
  float inv = 1.f / ss;
  float cs[4];
#pragma unroll
  for (int r = 0; r < 4; ++r) {
    float p = e[r] * inv;                    // pre_norm_attn (no EPS)
    size_t sf = ((size_t)b * 16 + (hi << 2) + r) * 4096 + f0 + lo;
    if (attn_out) attn_out[sf] = p;
    unsigned short uu = f2bf(p + 1e-8f);
    attn_sf[sf] = uu;
    cs[r] = bf2f_lo(uu);                     // rounded value -> consistent fsum
  }
#pragma unroll
  for (int m = 1; m < 16; m <<= 1) {
#pragma unroll
    for (int r = 0; r < 4; ++r) cs[r] += __shfl_xor(cs[r], m);
  }
  if (lo == 0) {
    int tile = f0 >> 4;
    float* dst = fsumP + ((size_t)b * 256 + tile) * 16 + (hi << 2);
    dst[0] = cs[0]; dst[1] = cs[1]; dst[2] = cs[2]; dst[3] = cs[3];
  }
}

// inv_fsum[b,s] = 1 / sum_tiles fsumP
__global__ void fsum_reduce_kernel(const float* __restrict__ fsumP, float* __restrict__ invf) {
  int t = blockIdx.x * 256 + threadIdx.x;
  if (t >= 1024) return;
  int b = t >> 4, s = t & 15;
  const float* p = fsumP + (size_t)b * 256 * 16 + s;
  float acc = 0.f;
#pragma unroll 8
  for (int i = 0; i < 256; ++i) acc += p[i * 16];
  invf[t] = 1.f / acc;
}

// ---------------------------------------------------------------------------
// updates' GEMM: upd'[b,s,d] = invf[b,s] * sum_f attn[b,s,f]*f_normT[b,d,f]
// grid (512/64, B), 4 waves n-adjacent, wave 16(s) x 16(d), K=4096.
// ---------------------------------------------------------------------------
__global__ __launch_bounds__(256) void upd_gemm_kernel(
    const unsigned short* __restrict__ attn,  // [B,16,4096]
    const unsigned short* __restrict__ FnT,   // [B,512,4096]
    const float* __restrict__ invf,           // [1024]
    unsigned short* __restrict__ outb) {      // [1024,512] bf16
  int b = blockIdx.y;
  int w = threadIdx.x >> 6, lane = threadIdx.x & 63;
  int lo = lane & 15, hi = lane >> 4;
  int n0 = (blockIdx.x << 6) + (w << 4);
  const unsigned short* Ap = attn + ((size_t)b * 16 + lo) * 4096 + (hi << 3);
  const unsigned short* Bp = FnT + ((size_t)b * 512 + n0 + lo) * 4096 + (hi << 3);
  f32x4 acc = {0.f, 0.f, 0.f, 0.f};
#pragma unroll 4
  for (int kk = 0; kk < 4096; kk += 32) {
    bf16x8 a = *reinterpret_cast<const bf16x8*>(Ap + kk);
    bf16x8 bb = *reinterpret_cast<const bf16x8*>(Bp + kk);
    acc = __builtin_amdgcn_mfma_f32_16x16x32_bf16(a, bb, acc, 0, 0, 0);
  }
  float4 iv = *reinterpret_cast<const float4*>(invf + (b << 4) + (hi << 2));
  float ivv[4] = {iv.x, iv.y, iv.z, iv.w};
#pragma unroll
  for (int r = 0; r < 4; ++r)
    outb[((size_t)b * 16 + (hi << 2) + r) * 512 + n0 + lo] = f2bf(acc[r] * ivv[r]);
}

// ---------------------------------------------------------------------------
// GRU combine + fused LayerNorm(mlp_ln) -> slots_c, h_ln bf16
// ---------------------------------------------------------------------------
__global__ __launch_bounds__(256) void gru_ln_kernel(
    const float* __restrict__ gi, const float* __restrict__ gh,
    const float* __restrict__ sn, const float* __restrict__ mg,
    const float* __restrict__ mb, float* __restrict__ slots,
    unsigned short* __restrict__ hln) {
  __shared__ float red[8];
  int row = blockIdx.x;
  int t = threadIdx.x;
  const float* gir = gi + (size_t)row * 1536;
  const float* ghr = gh + (size_t)row * 1536;
  float2 ir = *reinterpret_cast<const float2*>(gir + t * 2);
  float2 iz = *reinterpret_cast<const float2*>(gir + 512 + t * 2);
  float2 in_ = *reinterpret_cast<const float2*>(gir + 1024 + t * 2);
  float2 hr = *reinterpret_cast<const float2*>(ghr + t * 2);
  float2 hz = *reinterpret_cast<const float2*>(ghr + 512 + t * 2);
  float2 hn = *reinterpret_cast<const float2*>(ghr + 1024 + t * 2);
  float2 hp = *reinterpret_cast<const float2*>(sn + (size_t)row * 512 + t * 2);
  float h[2], iv[2] = {in_.x, in_.y}, hv[2] = {hn.x, hn.y};
  float rr[2] = {ir.x + hr.x, ir.y + hr.y}, zz[2] = {iz.x + hz.x, iz.y + hz.y};
  float pp[2] = {hp.x, hp.y};
#pragma unroll
  for (int k = 0; k < 2; ++k) {
    float r = 1.f / (1.f + __expf(-rr[k]));
    float z = 1.f / (1.f + __expf(-zz[k]));
    float a = iv[k] + r * hv[k];
    float ee = __expf(-2.f * fabsf(a));
    float nt = (1.f - ee) / (1.f + ee);
    float n = copysignf(nt, a);
    h[k] = (1.f - z) * n + z * pp[k];
  }
  *reinterpret_cast<float2*>(slots + (size_t)row * 512 + t * 2) = make_float2(h[0], h[1]);
  float s = h[0] + h[1], q = h[0] * h[0] + h[1] * h[1];
#pragma unroll
  for (int off = 32; off; off >>= 1) { s += __shfl_xor(s, off); q += __shfl_xor(q, off); }
  int w = t >> 6, lane = t & 63;
  if (lane == 0) { red[w] = s; red[4 + w] = q; }
  __syncthreads();
  s = red[0] + red[1] + red[2] + red[3];
  q = red[4] + red[5] + red[6] + red[7];
  float mu = s * (1.f / 512.f);
  float var = q * (1.f / 512.f) - mu * mu;
  float rstd = rsqrtf(var + 1e-5f);
  float y0 = (h[0] - mu) * rstd * mg[t * 2] + mb[t * 2];
  float y1 = (h[1] - mu) * rstd * mg[t * 2 + 1] + mb[t * 2 + 1];
  *reinterpret_cast<unsigned int*>(hln + (size_t)row * 512 + t * 2) =
      (unsigned)f2bf(y0) | ((unsigned)f2bf(y1) << 16);
}

// ---------------------------------------------------------------------------
extern "C" void kernel_launch(void* const* d_in, const int* in_sizes, int n_in,
                              void* d_out, int out_size, void* d_ws, size_t ws_size,
                              hipStream_t stream) {
  const float* slots_in  = (const float*)d_in[0];
  const float* features  = (const float*)d_in[1];
  const float* ln_feat_g = (const float*)d_in[2];
  const float* ln_feat_b = (const float*)d_in[3];
  const float* ln_slot_g = (const float*)d_in[4];
  const float* ln_slot_b = (const float*)d_in[5];
  const float* w_k  = (const float*)d_in[6];
  const float* w_v  = (const float*)d_in[7];
  const float* w_q  = (const float*)d_in[8];
  const float* w_ih = (const float*)d_in[9];
  const float* w_hh = (const float*)d_in[10];
  const float* b_ih = (const float*)d_in[11];
  const float* b_hh = (const float*)d_in[12];
  const float* mlp_ln_g = (const float*)d_in[13];
  const float* mlp_ln_b = (const float*)d_in[14];
  const float* w1 = (const float*)d_in[15];
  const float* b1 = (const float*)d_in[16];
  const float* w2 = (const float*)d_in[17];
  const float* b2 = (const float*)d_in[18];

  char* ws = (char*)d_ws;
  size_t off = 0;
  auto alloc = [&](size_t bytes) {
    char* p = ws + off;
    off += (bytes + 255) & ~(size_t)255;
    return p;
  };
  unsigned short* f_norm  = (unsigned short*)alloc((size_t)64 * 4096 * 512 * 2);  // 256MB
  unsigned short* f_normT = (unsigned short*)alloc((size_t)64 * 512 * 4096 * 2);  // 256MB
  unsigned short* attn_sf = (unsigned short*)alloc((size_t)64 * 16 * 4096 * 2);   // 8MB
  unsigned short* qp_bf   = (unsigned short*)alloc(1024 * 512 * 2);
  float*          s_n_f   = (float*)alloc(1024 * 512 * 4);
  unsigned short* s_n_bf  = (unsigned short*)alloc(1024 * 512 * 2);
  float*          fsumP   = (float*)alloc(64 * 256 * 16 * 4);
  float*          invf    = (float*)alloc(1024 * 4);
  unsigned short* updp_bf = (unsigned short*)alloc(1024 * 512 * 2);
  float*          gi      = (float*)alloc(1024 * 1536 * 4);
  float*          gh      = (float*)alloc(1024 * 1536 * 4);
  float*          slots_c = (float*)alloc(1024 * 512 * 4);
  unsigned short* hln_bf  = (unsigned short*)alloc(1024 * 512 * 2);
  unsigned short* hm_bf   = (unsigned short*)alloc((size_t)1024 * 2048 * 2);
  unsigned short* Bcat    = (unsigned short*)alloc((size_t)2048 * 512 * 2);  // [WqkT; Whh]
  unsigned short* Wih_bf  = (unsigned short*)alloc(1536 * 512 * 2);
  unsigned short* WkT_bf  = (unsigned short*)alloc(512 * 512 * 2);
  unsigned short* WqT_bf  = (unsigned short*)alloc(512 * 512 * 2);
  unsigned short* WvT_bf  = (unsigned short*)alloc(512 * 512 * 2);
  unsigned short* Wc2_bf  = (unsigned short*)alloc(1536 * 512 * 2);  // wih@wv
  unsigned short* W1_bf   = (unsigned short*)alloc((size_t)2048 * 512 * 2);
  unsigned short* W2_bf   = (unsigned short*)alloc((size_t)512 * 2048 * 2);

  float* out_slots = (float*)d_out;               // [64,16,512]
  float* out_attn  = out_slots + 1024 * 512;      // [64,16,4096]

  // --- setup: weight conversions + composites (once) ---
  cvt_bf16_kernel<<<dim3(768), dim3(256), 0, stream>>>(w_hh, Bcat + 512 * 512, 196608);
  cvt_bf16_kernel<<<dim3(768), dim3(256), 0, stream>>>(w_ih, Wih_bf, 196608);
  cvt_bf16_kernel<<<dim3(1024), dim3(256), 0, stream>>>(w1, W1_bf, 262144);
  cvt_bf16_kernel<<<dim3(1024), dim3(256), 0, stream>>>(w2, W2_bf, 262144);
  transpose_cvt_kernel<<<dim3(1024), dim3(256), 0, stream>>>(w_k, WkT_bf);
  transpose_cvt_kernel<<<dim3(1024), dim3(256), 0, stream>>>(w_q, WqT_bf);
  transpose_cvt_kernel<<<dim3(1024), dim3(256), 0, stream>>>(w_v, WvT_bf);
  // WqkT = wk^T @ wq  -> Bcat rows 0..511
  gemm_nt<0><<<dim3(4, 16), dim3(256), 0, stream>>>(
      WkT_bf, WqT_bf, nullptr, nullptr, nullptr, Bcat, 512, 512, 512);
  // Wc2 = wih @ wv
  gemm_nt<0><<<dim3(4, 48), dim3(256), 0, stream>>>(
      Wih_bf, WvT_bf, nullptr, nullptr, nullptr, Wc2_bf, 1536, 512, 512);
  // f_norm = LN(features) -> bf16; then transpose
  ln512_kernel<0><<<dim3(65536), dim3(256), 0, stream>>>(
      features, ln_feat_g, ln_feat_b, f_norm, nullptr, 262144);
  transpose_fnorm_kernel<<<dim3(64, 8, 64), dim3(256), 0, stream>>>(f_norm, f_normT);

  for (int it = 0; it < 3; ++it) {
    const float* slots_src = (it == 0) ? slots_in : slots_c;
    // s_n = LN(slots)
    ln512_kernel<1><<<dim3(256), dim3(256), 0, stream>>>(
        slots_src, ln_slot_g, ln_slot_b, s_n_bf, s_n_f, 1024);
    // [qp | gh] = s_n @ [WqkT; Whh]^T  (split epilogue, gh gets b_hh)
    gemm_nt<1><<<dim3(16, 32), dim3(256), 0, stream>>>(
        s_n_bf, Bcat, b_hh, nullptr, gh, qp_bf, 1024, 2048, 512);
    // dots + softmax over slots (+ pre_norm out on last iter)
    dots_softmax_kernel<<<dim3(64, 64), dim3(256), 0, stream>>>(
        qp_bf, f_norm, attn_sf, fsumP, (it == 2) ? out_attn : nullptr);
    fsum_reduce_kernel<<<dim3(4), dim3(256), 0, stream>>>(fsumP, invf);
    // updates' = (attn/fsum) @ f_norm  via f_normT GEMM
    upd_gemm_kernel<<<dim3(8, 64), dim3(256), 0, stream>>>(attn_sf, f_normT, invf, updp_bf);
    // gi = updates' @ (wih@wv)^T + b_ih
    gemm_nt<2><<<dim3(12, 32), dim3(256), 0, stream>>>(
        updp_bf, Wc2_bf, b_ih, nullptr, gi, nullptr, 1024, 1536, 512);
    // GRU combine + LN(mlp_ln)
    gru_ln_kernel<<<dim3(1024), dim3(256), 0, stream>>>(
        gi, gh, s_n_f, mlp_ln_g, mlp_ln_b, slots_c, hln_bf);
    // MLP
    gemm_nt<3><<<dim3(16, 32), dim3(256), 0, stream>>>(
        hln_bf, W1_bf, b1, nullptr, nullptr, hm_bf, 1024, 2048, 512);
    float* slot_dst = (it == 2) ? out_slots : slots_c;
    gemm_nt<4><<<dim3(4, 32), dim3(256), 0, stream>>>(
        hm_bf, W2_bf, b2, slots_c, slot_dst, nullptr, 1024, 512, 2048);
  }
  (void)in_sizes; (void)n_in; (void)out_size; (void)ws_size;
}